// Round 5
// baseline (129.981 us; speedup 1.0000x reference)
//
#include <hip/hip_runtime.h>

static constexpr int IMG = 512;
static constexpr int TX  = 64;           // tile width  (output)
static constexpr int TY  = 16;           // tile height (output)
static constexpr int LST = 72;           // LDS row stride (floats)
static constexpr int SROWS  = TY + 6;    // 22 staged rows (r <-> y = ty0-3+r)
static constexpr int NSTAGE = SROWS * 18; // 396 float4 staging items

// g(d)*d with ZERO transcendentals:
//   t = 1+d^2 ; rinv via bit-trick seed + 1 Newton (rel err ~3e-3, full-rate ops)
//   v = |d| * rinv  (in [0, ~0.502] ALWAYS -- self-limiting, no clamp needed)
//   exp(-v) via degree-4 Taylor (alternating series err <= 0.5^5/120 = 2.6e-4)
__device__ __forceinline__ float gd_acc(float d, float acc) {
    const float t  = fmaf(d, d, 1.0f);
    float r = __uint_as_float(0x7EF311C3u - __float_as_uint(t));
    r = r * fmaf(-t, r, 2.0f);               // Newton: err^2
    const float v = __builtin_fabsf(d) * r;
    float e = fmaf(0.041666668f, v, -0.16666667f);
    e = fmaf(e, v, 0.5f);
    e = fmaf(e, v, -1.0f);
    e = fmaf(e, v, 1.0f);                    // ~exp(-v)
    return fmaf(e, d, acc);
}

// One diffusion step, single-wave block, 4 px/thread, prefetch-pipelined.
// Column maps: A(X0): x = tx0-4+c ; B(X1): x = tx0-2+c ; A(X2): x = tx0-1+c.
template<int WOFF, int NR, int RLO, int NG, bool TO_GLOBAL>
__device__ __forceinline__ void diffuse_step(
    const float* __restrict__ prev, float* __restrict__ cur,
    const float* __restrict__ Wt, const float* __restrict__ bt,
    int xoff, int ty0, int tx0, int tid, float* __restrict__ gout)
{
    constexpr int LOADW  = WOFF ? 8 : 6;
    constexpr int NITEMS = NR * NG;

    float L0[LOADW], L1[LOADW], L2[LOADW];
    {   // initial load (idx = tid; clamp if tid >= NITEMS, harmless)
        const int idx0 = (tid < NITEMS) ? tid : 0;
        const int rr = idx0 / NG, j = idx0 - rr * NG;
        const float* base = prev + (RLO + rr - 1) * LST + 4 * j;
        *(float4*)&L0[0] = *(const float4*)(base);
        *(float4*)&L1[0] = *(const float4*)(base + LST);
        *(float4*)&L2[0] = *(const float4*)(base + 2 * LST);
        if (WOFF) {
            *(float4*)&L0[4] = *(const float4*)(base + 4);
            *(float4*)&L1[4] = *(const float4*)(base + LST + 4);
            *(float4*)&L2[4] = *(const float4*)(base + 2 * LST + 4);
        } else {
            *(float2*)&L0[4] = *(const float2*)(base + 4);
            *(float2*)&L1[4] = *(const float2*)(base + LST + 4);
            *(float2*)&L2[4] = *(const float2*)(base + 2 * LST + 4);
        }
    }

    for (int idx = tid; idx < NITEMS; idx += 64) {
        // ---- prefetch next item's window (issued before compute) ----
        float P0[LOADW], P1[LOADW], P2[LOADW];
        {
            const int nidx = (idx + 64 < NITEMS) ? (idx + 64) : idx;
            const int rr = nidx / NG, j = nidx - rr * NG;
            const float* base = prev + (RLO + rr - 1) * LST + 4 * j;
            *(float4*)&P0[0] = *(const float4*)(base);
            *(float4*)&P1[0] = *(const float4*)(base + LST);
            *(float4*)&P2[0] = *(const float4*)(base + 2 * LST);
            if (WOFF) {
                *(float4*)&P0[4] = *(const float4*)(base + 4);
                *(float4*)&P1[4] = *(const float4*)(base + LST + 4);
                *(float4*)&P2[4] = *(const float4*)(base + 2 * LST + 4);
            } else {
                *(float2*)&P0[4] = *(const float2*)(base + 4);
                *(float2*)&P1[4] = *(const float2*)(base + LST + 4);
                *(float2*)&P2[4] = *(const float2*)(base + 2 * LST + 4);
            }
        }

        // ---- compute current item ----
        const int rr = idx / NG, j = idx - rr * NG;
        const int r  = RLO + rr, c0 = 4 * j;

        float acc[4] = {0.f, 0.f, 0.f, 0.f};
#pragma unroll
        for (int k = 0; k < 8; ++k) {
            const float w0 = Wt[9*k+0], w1 = Wt[9*k+1], w2 = Wt[9*k+2];
            const float w3 = Wt[9*k+3], w4 = Wt[9*k+4], w5 = Wt[9*k+5];
            const float w6 = Wt[9*k+6], w7 = Wt[9*k+7], w8 = Wt[9*k+8];
            const float bk = bt[k];
#pragma unroll
            for (int i = 0; i < 4; ++i) {
                float d = bk;
                d = fmaf(w0, L0[WOFF+i],   d);
                d = fmaf(w1, L0[WOFF+i+1], d);
                d = fmaf(w2, L0[WOFF+i+2], d);
                d = fmaf(w3, L1[WOFF+i],   d);
                d = fmaf(w4, L1[WOFF+i+1], d);
                d = fmaf(w5, L1[WOFF+i+2], d);
                d = fmaf(w6, L2[WOFF+i],   d);
                d = fmaf(w7, L2[WOFF+i+1], d);
                d = fmaf(w8, L2[WOFF+i+2], d);
                acc[i] = gd_acc(d, acc[i]);
            }
        }

        float4 v;
        v.x = L1[WOFF+1] - acc[0] * 0.125f;
        v.y = L1[WOFF+2] - acc[1] * 0.125f;
        v.z = L1[WOFF+3] - acc[2] * 0.125f;
        v.w = L1[WOFF+4] - acc[3] * 0.125f;

        const int gy = ty0 - 3 + r;
        if (TO_GLOBAL) {
            *(float4*)&gout[gy * IMG + tx0 + c0] = v;
        } else {
            const bool ry  = (unsigned)gy < (unsigned)IMG;
            const int  gx0 = xoff + c0;
            v.x = (ry && (unsigned)(gx0 + 0) < (unsigned)IMG) ? v.x : 0.f;
            v.y = (ry && (unsigned)(gx0 + 1) < (unsigned)IMG) ? v.y : 0.f;
            v.z = (ry && (unsigned)(gx0 + 2) < (unsigned)IMG) ? v.z : 0.f;
            v.w = (ry && (unsigned)(gx0 + 3) < (unsigned)IMG) ? v.w : 0.f;
            *(float4*)&cur[r * LST + c0] = v;
        }

        // rotate prefetched window in (regs, elided by renaming/unroll)
#pragma unroll
        for (int q = 0; q < LOADW; ++q) { L0[q] = P0[q]; L1[q] = P1[q]; L2[q] = P2[q]; }
    }
}

__global__ __launch_bounds__(64) void deep_ad_kernel(
    const float* __restrict__ x, const float* __restrict__ W,
    const float* __restrict__ b, float* __restrict__ out)
{
    __shared__ float A[SROWS * LST];   // X0, later reused for X2
    __shared__ float Bs[SROWS * LST];  // X1

    const int tid = threadIdx.x;
    const int tx0 = blockIdx.x * TX;
    const int ty0 = blockIdx.y * TY;
    const float* xin  = x   + (size_t)blockIdx.z * (IMG * IMG);
    float*       gout = out + (size_t)blockIdx.z * (IMG * IMG);

    // Stage X0 (22 rows x 72 cols): issue all loads first, one wait, then LDS writes.
    {
        float4 sv[7];
#pragma unroll
        for (int q = 0; q < 7; ++q) {
            const int item = tid + 64 * q;
            const int rr = item / 18, j = item - rr * 18;
            const int gy = ty0 - 3 + rr;
            const int gx = tx0 - 4 + 4 * j;
            float4 v = {0.f, 0.f, 0.f, 0.f};
            if (item < NSTAGE && (unsigned)gy < (unsigned)IMG && (unsigned)gx < (unsigned)IMG)
                v = *(const float4*)(xin + gy * IMG + gx);
            sv[q] = v;
        }
#pragma unroll
        for (int q = 0; q < 7; ++q) {
            const int item = tid + 64 * q;
            if (item < NSTAGE) *(float4*)&A[item * 4] = sv[q];
        }
    }
    __syncthreads();   // single-wave block: no cross-wave phase-locking

    // step1: rows r=1..20 (y: ty0-2..ty0+17), 17 groups (x: tx0-2..tx0+65) -> Bs
    diffuse_step<1, TY + 4, 1, 17, false>(A,  Bs, W + 0,   b + 0,  tx0 - 2, ty0, tx0, tid, nullptr);
    __syncthreads();
    // step2: rows r=2..19, 17 groups (x: tx0-1..tx0+66; last 2 cols garbage, never read) -> A
    diffuse_step<0, TY + 2, 2, 17, false>(Bs, A,  W + 72,  b + 8,  tx0 - 1, ty0, tx0, tid, nullptr);
    __syncthreads();
    // step3: rows r=3..18 (y: ty0..ty0+15), 16 groups (x: tx0..tx0+63) -> global
    diffuse_step<0, TY,     3, 16, true >(A, nullptr, W + 144, b + 16, 0, ty0, tx0, tid, gout);
}

extern "C" void kernel_launch(void* const* d_in, const int* in_sizes, int n_in,
                              void* d_out, int out_size, void* d_ws, size_t ws_size,
                              hipStream_t stream)
{
    const float* x = (const float*)d_in[0];
    const float* W = (const float*)d_in[1];  // [3,8,1,3,3]
    const float* b = (const float*)d_in[2];  // [3,8]
    float* out = (float*)d_out;
    const int N = in_sizes[0] / (IMG * IMG); // 16
    dim3 grid(IMG / TX, IMG / TY, N);
    deep_ad_kernel<<<grid, 64, 0, stream>>>(x, W, b, out);
}

// Round 6
// 125.645 us; speedup vs baseline: 1.0345x; 1.0345x over previous
//
#include <hip/hip_runtime.h>

static constexpr int IMG = 512;
static constexpr int TX  = 64;            // tile width  (output)
static constexpr int TY  = 32;            // tile height (output)
static constexpr int NT  = 128;           // 2 waves per block
static constexpr int LST = 72;            // LDS row stride (floats)
static constexpr int SROWS  = TY + 6;     // 38 staged rows (r <-> y = ty0-3+r)
static constexpr int NSTAGE = SROWS * 18; // 684 float4 staging items

// One diffusion step, 4 px/thread, fixed-trip unrolled + prefetch pipeline.
// Column maps: A(X0): x = tx0-4+c ; B(X1): x = tx0-2+c ; A(X2): x = tx0-1+c.
// WOFF=1: load 8 floats/row, window L[i+1..i+3]. WOFF=0: 6 floats, L[i..i+2].
template<int WOFF, int NR, int RLO, int NG, bool TO_GLOBAL>
__device__ __forceinline__ void diffuse_step(
    const float* __restrict__ prev, float* __restrict__ cur,
    const float* __restrict__ Wt, const float* __restrict__ bt,
    int xoff, int ty0, int tx0, int tid, float* __restrict__ gout)
{
    constexpr int LOADW  = WOFF ? 8 : 6;
    constexpr int NITEMS = NR * NG;
    constexpr int TRIPS  = (NITEMS + NT - 1) / NT;

    float L0[LOADW], L1[LOADW], L2[LOADW];
    {   // load for trip 0 (clamped)
        const int cidx = (tid < NITEMS) ? tid : (NITEMS - 1);
        const int rr = cidx / NG, j = cidx - rr * NG;
        const float* base = prev + (RLO + rr - 1) * LST + 4 * j;
        *(float4*)&L0[0] = *(const float4*)(base);
        *(float4*)&L1[0] = *(const float4*)(base + LST);
        *(float4*)&L2[0] = *(const float4*)(base + 2 * LST);
        if (WOFF) {
            *(float4*)&L0[4] = *(const float4*)(base + 4);
            *(float4*)&L1[4] = *(const float4*)(base + LST + 4);
            *(float4*)&L2[4] = *(const float4*)(base + 2 * LST + 4);
        } else {
            *(float2*)&L0[4] = *(const float2*)(base + 4);
            *(float2*)&L1[4] = *(const float2*)(base + LST + 4);
            *(float2*)&L2[4] = *(const float2*)(base + 2 * LST + 4);
        }
    }

#pragma unroll
    for (int q = 0; q < TRIPS; ++q) {
        const int idx = tid + q * NT;

        // ---- prefetch next trip's window (renamed away by unroll) ----
        float P0[LOADW], P1[LOADW], P2[LOADW];
        if (q + 1 < TRIPS) {
            const int nidx = (tid + (q + 1) * NT < NITEMS) ? (tid + (q + 1) * NT)
                                                           : (NITEMS - 1);
            const int rr = nidx / NG, j = nidx - rr * NG;
            const float* base = prev + (RLO + rr - 1) * LST + 4 * j;
            *(float4*)&P0[0] = *(const float4*)(base);
            *(float4*)&P1[0] = *(const float4*)(base + LST);
            *(float4*)&P2[0] = *(const float4*)(base + 2 * LST);
            if (WOFF) {
                *(float4*)&P0[4] = *(const float4*)(base + 4);
                *(float4*)&P1[4] = *(const float4*)(base + LST + 4);
                *(float4*)&P2[4] = *(const float4*)(base + 2 * LST + 4);
            } else {
                *(float2*)&P0[4] = *(const float2*)(base + 4);
                *(float2*)&P1[4] = *(const float2*)(base + LST + 4);
                *(float2*)&P2[4] = *(const float2*)(base + 2 * LST + 4);
            }
        }

        // ---- compute current item ----
        const int cidx = (idx < NITEMS) ? idx : (NITEMS - 1);
        const int rr = cidx / NG, j = cidx - rr * NG;
        const int r  = RLO + rr, c0 = 4 * j;

        float acc[4] = {0.f, 0.f, 0.f, 0.f};
#pragma unroll
        for (int k = 0; k < 8; ++k) {
            const float w0 = Wt[9*k+0], w1 = Wt[9*k+1], w2 = Wt[9*k+2];
            const float w3 = Wt[9*k+3], w4 = Wt[9*k+4], w5 = Wt[9*k+5];
            const float w6 = Wt[9*k+6], w7 = Wt[9*k+7], w8 = Wt[9*k+8];
            const float bk = bt[k];
#pragma unroll
            for (int i = 0; i < 4; ++i) {
                float d = bk;
                d = fmaf(w0, L0[WOFF+i],   d);
                d = fmaf(w1, L0[WOFF+i+1], d);
                d = fmaf(w2, L0[WOFF+i+2], d);
                d = fmaf(w3, L1[WOFF+i],   d);
                d = fmaf(w4, L1[WOFF+i+1], d);
                d = fmaf(w5, L1[WOFF+i+2], d);
                d = fmaf(w6, L2[WOFF+i],   d);
                d = fmaf(w7, L2[WOFF+i+1], d);
                d = fmaf(w8, L2[WOFF+i+2], d);
                const float t    = fmaf(d, d, 1.0f);
                const float rinv = __builtin_amdgcn_rcpf(t);
                const float e    = __builtin_amdgcn_exp2f(
                                       -1.442695040888963f * __builtin_fabsf(d) * rinv);
                acc[i] = fmaf(e, d, acc[i]);
            }
        }

        float4 v;
        v.x = L1[WOFF+1] - acc[0] * 0.125f;
        v.y = L1[WOFF+2] - acc[1] * 0.125f;
        v.z = L1[WOFF+3] - acc[2] * 0.125f;
        v.w = L1[WOFF+4] - acc[3] * 0.125f;

        const int gy = ty0 - 3 + r;
        if (TO_GLOBAL) {
            if (idx < NITEMS)
                *(float4*)&gout[gy * IMG + tx0 + c0] = v;
        } else {
            const bool ry  = (unsigned)gy < (unsigned)IMG;
            const int  gx0 = xoff + c0;
            v.x = (ry && (unsigned)(gx0 + 0) < (unsigned)IMG) ? v.x : 0.f;
            v.y = (ry && (unsigned)(gx0 + 1) < (unsigned)IMG) ? v.y : 0.f;
            v.z = (ry && (unsigned)(gx0 + 2) < (unsigned)IMG) ? v.z : 0.f;
            v.w = (ry && (unsigned)(gx0 + 3) < (unsigned)IMG) ? v.w : 0.f;
            if (idx < NITEMS)
                *(float4*)&cur[r * LST + c0] = v;
        }

#pragma unroll
        for (int qq = 0; qq < LOADW; ++qq) { L0[qq] = P0[qq]; L1[qq] = P1[qq]; L2[qq] = P2[qq]; }
    }
}

__global__ __launch_bounds__(NT) void deep_ad_kernel(
    const float* __restrict__ x, const float* __restrict__ W,
    const float* __restrict__ b, float* __restrict__ out)
{
    __shared__ float A[SROWS * LST];   // X0, later reused for X2
    __shared__ float Bs[SROWS * LST];  // X1

    const int tid = threadIdx.x;
    const int tx0 = blockIdx.x * TX;
    const int ty0 = blockIdx.y * TY;
    const float* xin  = x   + (size_t)blockIdx.z * (IMG * IMG);
    float*       gout = out + (size_t)blockIdx.z * (IMG * IMG);

    // Stage X0 (38 rows x 72 cols): issue all loads, one wait, then LDS writes.
    {
        constexpr int SQ = (NSTAGE + NT - 1) / NT;   // 6 rounds
        float4 sv[SQ];
#pragma unroll
        for (int q = 0; q < SQ; ++q) {
            const int item = tid + NT * q;
            const int rr = item / 18, j = item - rr * 18;
            const int gy = ty0 - 3 + rr;
            const int gx = tx0 - 4 + 4 * j;
            float4 v = {0.f, 0.f, 0.f, 0.f};
            if (item < NSTAGE && (unsigned)gy < (unsigned)IMG && (unsigned)gx < (unsigned)IMG)
                v = *(const float4*)(xin + gy * IMG + gx);
            sv[q] = v;
        }
#pragma unroll
        for (int q = 0; q < SQ; ++q) {
            const int item = tid + NT * q;
            if (item < NSTAGE) *(float4*)&A[item * 4] = sv[q];
        }
    }
    __syncthreads();

    // step1: rows r=1..36 (y: ty0-2..ty0+33), 17 groups (x: tx0-2..tx0+65) -> Bs
    diffuse_step<1, TY + 4, 1, 17, false>(A,  Bs, W + 0,   b + 0,  tx0 - 2, ty0, tx0, tid, nullptr);
    __syncthreads();
    // step2: rows r=2..35, 17 groups (x: tx0-1..tx0+66; overhang cols dead) -> A
    diffuse_step<0, TY + 2, 2, 17, false>(Bs, A,  W + 72,  b + 8,  tx0 - 1, ty0, tx0, tid, nullptr);
    __syncthreads();
    // step3: rows r=3..34 (y: ty0..ty0+31), 16 groups (x: tx0..tx0+63) -> global
    diffuse_step<0, TY,     3, 16, true >(A, nullptr, W + 144, b + 16, 0, ty0, tx0, tid, gout);
}

extern "C" void kernel_launch(void* const* d_in, const int* in_sizes, int n_in,
                              void* d_out, int out_size, void* d_ws, size_t ws_size,
                              hipStream_t stream)
{
    const float* x = (const float*)d_in[0];
    const float* W = (const float*)d_in[1];  // [3,8,1,3,3]
    const float* b = (const float*)d_in[2];  // [3,8]
    float* out = (float*)d_out;
    const int N = in_sizes[0] / (IMG * IMG); // 16
    dim3 grid(IMG / TX, IMG / TY, N);
    deep_ad_kernel<<<grid, NT, 0, stream>>>(x, W, b, out);
}